// Round 9
// baseline (2484.980 us; speedup 1.0000x reference)
//
#include <hip/hip_runtime.h>
#include <cstdint>
#include <cstddef>

// PConv, round 9: decomposition round 2.
// Graph: cvt -> A(loads x8) -> B(stores x8) -> D(vec-gather x8)
//        -> E(new 16x16x16 all-lane kernel x3, d_out) -> C(proven R7 pass x1, d_out last).
// C rewrites every output byte, so d_out is correct regardless of E.
// x8/x3 repeats force all probe dispatches above the ~250us harness fills in top-5.

namespace {
constexpr int B_   = 2;
constexpr int N_   = 50000;
constexpr int M_   = 50000;
constexpr int KNB  = 16;
constexpr int CIN  = 64;
constexpr int COUT = 67 * 16;      // 1072
constexpr int PAIRS = B_ * M_;     // 100000
constexpr int FELEMS = B_ * N_ * CIN;   // 6,400,000
constexpr size_t SINK_OFF_A = 16u * 1024 * 1024;
constexpr size_t SINK_OFF_D = 20u * 1024 * 1024;
}

typedef unsigned int u32;
typedef float  f32x4   __attribute__((ext_vector_type(4)));
typedef short  short8  __attribute__((ext_vector_type(8)));
typedef short  short4v __attribute__((ext_vector_type(4)));
typedef u32    u32x4   __attribute__((ext_vector_type(4)));
typedef u32    u32x2   __attribute__((ext_vector_type(2)));

struct IdxS   { int v[16]; };
struct StageT { unsigned short bg[4][8]; float ad[8]; float wf[8]; };
struct StageF { float bg[4][8]; float ad[8]; float wf[8]; };

static __device__ __forceinline__ short8 pack_bf8(const float* x) {
  u32x4 w;
  #pragma unroll
  for (int q = 0; q < 4; ++q)
    w[q] = __builtin_amdgcn_perm(__builtin_bit_cast(u32, x[2*q+1]),
                                 __builtin_bit_cast(u32, x[2*q]),
                                 0x07060302u);
  return __builtin_bit_cast(short8, w);
}

static __device__ __forceinline__ short4v pack_bf4(const float* x) {
  u32x2 w;
  #pragma unroll
  for (int q = 0; q < 2; ++q)
    w[q] = __builtin_amdgcn_perm(__builtin_bit_cast(u32, x[2*q+1]),
                                 __builtin_bit_cast(u32, x[2*q]),
                                 0x07060302u);
  return __builtin_bit_cast(short4v, w);
}

static __device__ __forceinline__ u32 bfrne(float x) {
  u32 u = __builtin_bit_cast(u32, x);
  return (u + 0x7FFFu + ((u >> 16) & 1u)) >> 16;
}

// ---------------- pre-pass: f32 -> bf16 table ----------------
__global__ __launch_bounds__(256)
void cvt_feat_bf16(const float* __restrict__ src, unsigned short* __restrict__ dst) {
  const int n4 = FELEMS / 4;
  int i = blockIdx.x * blockDim.x + threadIdx.x;
  const int stride = gridDim.x * blockDim.x;
  const f32x4* s4 = reinterpret_cast<const f32x4*>(src);
  for (; i < n4; i += stride) {
    f32x4 v = s4[i];
    u32x2 w;
    w[0] = bfrne(v[0]) | (bfrne(v[1]) << 16);
    w[1] = bfrne(v[2]) | (bfrne(v[3]) << 16);
    *reinterpret_cast<u32x2*>(dst + 4 * (size_t)i) = w;
  }
}

// ---------------- shared helpers (R7-identical) ----------------
static __device__ __forceinline__ void load_idx(const int* __restrict__ idxp, IdxS& r) {
  #pragma unroll
  for (int j = 0; j < 16; ++j)
    r.v[j] = __builtin_amdgcn_readfirstlane(idxp[j]);
}

static __device__ __forceinline__ void load_stage_t(const unsigned short* __restrict__ fb,
                                                    const float* __restrict__ wnp,
                                                    const float* __restrict__ adp,
                                                    const IdxS& I, int lane, StageT& S) {
  const int cc = lane & 15;
  if (lane < 32) {
    const int hi = lane >> 4;
    int rows[8];
    #pragma unroll
    for (int j = 0; j < 8; ++j) rows[j] = hi ? I.v[j + 8] : I.v[j];
    #pragma unroll
    for (int j = 0; j < 8; ++j) {
      const u32 rb = ((u32)rows[j]) << 6;
      #pragma unroll
      for (int t = 0; t < 4; ++t)
        S.bg[t][j] = fb[rb + (u32)(t * 16 + cc)];
    }
    const u32 woff = (hi ? 128u : 0u) + (u32)cc;
    #pragma unroll
    for (int j = 0; j < 8; ++j)
      S.wf[j] = __builtin_nontemporal_load(wnp + woff + j * 16);
    if (cc < 3) {
      const u32 aoff = (hi ? 24u : 0u) + (u32)cc;
      #pragma unroll
      for (int j = 0; j < 8; ++j)
        S.ad[j] = __builtin_nontemporal_load(adp + aoff + j * 3);
    }
  }
}

static __device__ __forceinline__ void compute_store_t(const StageT& S,
                                                       float* __restrict__ op, int lane) {
  const int cc = lane & 15, g = lane >> 4;
  const int soff = cc * 16 + g * 4;
  const short8 a = pack_bf8(S.wf);
  #pragma unroll
  for (int t = 0; t < 4; ++t) {
    short8 b;
    #pragma unroll
    for (int j = 0; j < 8; ++j) b[j] = (short)S.bg[t][j];
    f32x4 acc = {0.f, 0.f, 0.f, 0.f};
    acc = __builtin_amdgcn_mfma_f32_16x16x32_bf16(a, b, acc, 0, 0, 0);
    __builtin_nontemporal_store(acc, reinterpret_cast<f32x4*>(op + soff + t * 256));
  }
  {
    const short8 b = pack_bf8(S.ad);
    f32x4 acc = {0.f, 0.f, 0.f, 0.f};
    acc = __builtin_amdgcn_mfma_f32_16x16x32_bf16(a, b, acc, 0, 0, 0);
    if (cc < 3)
      __builtin_nontemporal_store(acc, reinterpret_cast<f32x4*>(op + soff + 1024));
  }
}

// one full grid-stride sweep of the proven R7 structure
static __device__ __forceinline__ void pass_x32(const unsigned short* __restrict__ tbl,
                                                const int* __restrict__ inds,
                                                const float* __restrict__ wnet,
                                                const float* __restrict__ addf,
                                                float* __restrict__ out,
                                                int lane, int gw, int nw) {
  IdxS iCur, iNext;
  load_idx(inds + (size_t)gw * KNB, iCur);
  for (int p = gw; p < PAIRS; p += nw) {
    const int pn = (p + nw < PAIRS) ? (p + nw) : gw;
    load_idx(inds + (size_t)pn * KNB, iNext);
    const int b = (p >= M_) ? 1 : 0;
    StageT S = {};
    load_stage_t(tbl + (size_t)b * N_ * CIN, wnet + (size_t)p * 256,
                 addf + (size_t)p * 48, iCur, lane, S);
    compute_store_t(S, out + (size_t)p * COUT, lane);
    #pragma unroll
    for (int j = 0; j < 16; ++j) iCur.v[j] = iNext.v[j];
  }
}

// ---------------- A: load phase only, x8 ----------------
__global__ __launch_bounds__(256, 4)
void abl_loads(const unsigned short* __restrict__ tbl, const int* __restrict__ inds,
               const float* __restrict__ wnet, const float* __restrict__ addf,
               float* __restrict__ sink)
{
  const int lane = threadIdx.x & 63;
  const int gw = __builtin_amdgcn_readfirstlane(
      (int)((blockIdx.x * blockDim.x + threadIdx.x) >> 6));
  const int nw = (int)((gridDim.x * blockDim.x) >> 6);
  if (gw >= PAIRS) return;

  float acc = 0.f;
  #pragma unroll 1
  for (int r = 0; r < 8; ++r) {
    IdxS iCur, iNext;
    load_idx(inds + (size_t)gw * KNB, iCur);
    for (int p = gw; p < PAIRS; p += nw) {
      const int pn = (p + nw < PAIRS) ? (p + nw) : gw;
      load_idx(inds + (size_t)pn * KNB, iNext);
      const int b = (p >= M_) ? 1 : 0;
      StageT S = {};
      load_stage_t(tbl + (size_t)b * N_ * CIN, wnet + (size_t)p * 256,
                   addf + (size_t)p * 48, iCur, lane, S);
      int ui = 0;
      #pragma unroll
      for (int t = 0; t < 4; ++t)
        #pragma unroll
        for (int j = 0; j < 8; ++j) ui += S.bg[t][j];
      float fa = 0.f;
      #pragma unroll
      for (int j = 0; j < 8; ++j) fa += S.wf[j] + S.ad[j];
      acc += fa + (float)ui;
      #pragma unroll
      for (int j = 0; j < 16; ++j) iCur.v[j] = iNext.v[j];
    }
  }
  if (lane == 0) sink[gw] = acc;
}

// ---------------- B: compute+store phase only, x8 ----------------
__global__ __launch_bounds__(256, 4)
void abl_store(float* __restrict__ out)
{
  const int lane = threadIdx.x & 63;
  const int gw = __builtin_amdgcn_readfirstlane(
      (int)((blockIdx.x * blockDim.x + threadIdx.x) >> 6));
  const int nw = (int)((gridDim.x * blockDim.x) >> 6);
  if (gw >= PAIRS) return;

  StageT S;
  #pragma unroll
  for (int t = 0; t < 4; ++t)
    #pragma unroll
    for (int j = 0; j < 8; ++j) S.bg[t][j] = (unsigned short)(0x3f80 + lane + t + j);
  #pragma unroll
  for (int j = 0; j < 8; ++j) { S.ad[j] = 0.5f + j; S.wf[j] = 1.0f + lane * 0.01f; }

  #pragma unroll 1
  for (int r = 0; r < 8; ++r)
    for (int p = gw; p < PAIRS; p += nw)
      compute_store_t(S, out + (size_t)p * COUT, lane);
}

// ---------------- D: wide vectorized gather, x8 ----------------
__global__ __launch_bounds__(256, 4)
void abl_vecgather(const unsigned short* __restrict__ tbl, const int* __restrict__ inds,
                   float* __restrict__ sink)
{
  const int lane = threadIdx.x & 63;
  const int gw = __builtin_amdgcn_readfirstlane(
      (int)((blockIdx.x * blockDim.x + threadIdx.x) >> 6));
  const int nw = (int)((gridDim.x * blockDim.x) >> 6);
  if (gw >= PAIRS) return;

  const int kr  = lane >> 2;
  const int seg = lane & 3;
  u32 acc = 0;
  #pragma unroll 1
  for (int r = 0; r < 8; ++r) {
    IdxS iCur, iNext;
    load_idx(inds + (size_t)gw * KNB, iCur);
    for (int p = gw; p < PAIRS; p += nw) {
      const int pn = (p + nw < PAIRS) ? (p + nw) : gw;
      load_idx(inds + (size_t)pn * KNB, iNext);
      const int b = (p >= M_) ? 1 : 0;
      const unsigned short* fb = tbl + (size_t)b * N_ * CIN;
      const u32 rb = ((u32)iCur.v[kr]) << 6;
      const u32x4 v0 = *reinterpret_cast<const u32x4*>(fb + rb + seg * 8);
      const u32x4 v1 = *reinterpret_cast<const u32x4*>(fb + rb + 32 + seg * 8);
      #pragma unroll
      for (int q = 0; q < 4; ++q) acc += v0[q] + v1[q];
      #pragma unroll
      for (int j = 0; j < 16; ++j) iCur.v[j] = iNext.v[j];
    }
  }
  if (lane == 0) sink[gw] = (float)acc;
}

// ---------------- E: 16x16x16 all-lane kernel, x3, writes d_out (C overwrites) ----
__global__ __launch_bounds__(256, 8)
void pconv16(const unsigned short* __restrict__ tbl, const int* __restrict__ inds,
             const float* __restrict__ wnet, const float* __restrict__ addf,
             float* __restrict__ out)
{
  const int lane = threadIdx.x & 63;
  const int gw = __builtin_amdgcn_readfirstlane(
      (int)((blockIdx.x * blockDim.x + threadIdx.x) >> 6));
  const int nw = (int)((gridDim.x * blockDim.x) >> 6);
  if (gw >= PAIRS) return;

#if __has_builtin(__builtin_amdgcn_mfma_f32_16x16x16bf16_1k)
  const int cc = lane & 15, g = lane >> 4;
  #pragma unroll 1
  for (int r = 0; r < 3; ++r) {
    IdxS iCur, iNext;
    load_idx(inds + (size_t)gw * KNB, iCur);
    for (int p = gw; p < PAIRS; p += nw) {
      const int pn = (p + nw < PAIRS) ? (p + nw) : gw;
      load_idx(inds + (size_t)pn * KNB, iNext);
      const int b = (p >= M_) ? 1 : 0;
      const unsigned short* __restrict__ fb = tbl + (size_t)b * N_ * CIN;
      const float* __restrict__ wnp = wnet + (size_t)p * 256;
      const float* __restrict__ adp = addf + (size_t)p * 48;

      // A-frag: wn[k=4g+j][w=cc]  (all 64 lanes real, K=16 exact, no pad)
      float wf[4];
      #pragma unroll
      for (int j = 0; j < 4; ++j)
        wf[j] = __builtin_nontemporal_load(wnp + (4 * g + j) * 16 + cc);
      // B-frag: tbl[idx[4g+j]][16t+cc]
      unsigned short bg[4][4];
      #pragma unroll
      for (int j = 0; j < 4; ++j) {
        const u32 rb = ((u32)iCur.v[4 * g + j]) << 6;
        #pragma unroll
        for (int t = 0; t < 4; ++t)
          bg[t][j] = fb[rb + (u32)(t * 16 + cc)];
      }
      float ad[4];
      #pragma unroll
      for (int j = 0; j < 4; ++j)
        ad[j] = (cc < 3) ? __builtin_nontemporal_load(adp + (4 * g + j) * 3 + cc) : 0.f;

      const short4v a = pack_bf4(wf);
      float* __restrict__ op = out + (size_t)p * COUT;
      const int soff = cc * 16 + g * 4;
      #pragma unroll
      for (int t = 0; t < 4; ++t) {
        short4v bb;
        #pragma unroll
        for (int j = 0; j < 4; ++j) bb[j] = (short)bg[t][j];
        f32x4 acc = {0.f, 0.f, 0.f, 0.f};
        acc = __builtin_amdgcn_mfma_f32_16x16x16bf16_1k(a, bb, acc, 0, 0, 0);
        __builtin_nontemporal_store(acc, reinterpret_cast<f32x4*>(op + soff + t * 256));
      }
      {
        const short4v bb = pack_bf4(ad);
        f32x4 acc = {0.f, 0.f, 0.f, 0.f};
        acc = __builtin_amdgcn_mfma_f32_16x16x16bf16_1k(a, bb, acc, 0, 0, 0);
        if (cc < 3)
          __builtin_nontemporal_store(acc, reinterpret_cast<f32x4*>(op + soff + 1024));
      }
      #pragma unroll
      for (int j = 0; j < 16; ++j) iCur.v[j] = iNext.v[j];
    }
  }
#else
  // builtin absent on this toolchain: keep dispatch comparable (R7 body x3)
  #pragma unroll 1
  for (int r = 0; r < 3; ++r)
    pass_x32(tbl, inds, wnet, addf, out, lane, gw, nw);
#endif
}

// ---------------- C: proven R7 pass, x1, last writer of d_out ----------------
__global__ __launch_bounds__(256, 4)
void pconv9_tbl(const unsigned short* __restrict__ tbl, const int* __restrict__ inds,
                const float* __restrict__ wnet, const float* __restrict__ addf,
                float* __restrict__ out)
{
  const int lane = threadIdx.x & 63;
  const int gw = __builtin_amdgcn_readfirstlane(
      (int)((blockIdx.x * blockDim.x + threadIdx.x) >> 6));
  const int nw = (int)((gridDim.x * blockDim.x) >> 6);
  if (gw >= PAIRS) return;
  pass_x32(tbl, inds, wnet, addf, out, lane, gw, nw);
}

// ---------------- fallback (ws too small): R7-f32 single pass ----------------
static __device__ __forceinline__ void load_stage_f(const float* __restrict__ fb,
                                                    const float* __restrict__ wnp,
                                                    const float* __restrict__ adp,
                                                    const IdxS& I, int lane, StageF& S) {
  const int cc = lane & 15;
  if (lane < 32) {
    const int hi = lane >> 4;
    int rows[8];
    #pragma unroll
    for (int j = 0; j < 8; ++j) rows[j] = hi ? I.v[j + 8] : I.v[j];
    #pragma unroll
    for (int j = 0; j < 8; ++j) {
      const u32 rb = ((u32)rows[j]) << 6;
      #pragma unroll
      for (int t = 0; t < 4; ++t)
        S.bg[t][j] = fb[rb + (u32)(t * 16 + cc)];
    }
    const u32 woff = (hi ? 128u : 0u) + (u32)cc;
    #pragma unroll
    for (int j = 0; j < 8; ++j)
      S.wf[j] = __builtin_nontemporal_load(wnp + woff + j * 16);
    if (cc < 3) {
      const u32 aoff = (hi ? 24u : 0u) + (u32)cc;
      #pragma unroll
      for (int j = 0; j < 8; ++j)
        S.ad[j] = __builtin_nontemporal_load(adp + aoff + j * 3);
    }
  }
}

__global__ __launch_bounds__(256, 4)
void pconv9_f32(const float* __restrict__ feat, const int* __restrict__ inds,
                const float* __restrict__ wnet, const float* __restrict__ addf,
                float* __restrict__ out)
{
  const int lane = threadIdx.x & 63;
  const int gw = __builtin_amdgcn_readfirstlane(
      (int)((blockIdx.x * blockDim.x + threadIdx.x) >> 6));
  const int nw = (int)((gridDim.x * blockDim.x) >> 6);
  if (gw >= PAIRS) return;

  IdxS iCur, iNext;
  load_idx(inds + (size_t)gw * KNB, iCur);
  for (int p = gw; p < PAIRS; p += nw) {
    const int pn = (p + nw < PAIRS) ? (p + nw) : gw;
    load_idx(inds + (size_t)pn * KNB, iNext);
    const int b = (p >= M_) ? 1 : 0;
    StageF S = {};
    load_stage_f(feat + (size_t)b * N_ * CIN, wnet + (size_t)p * 256,
                 addf + (size_t)p * 48, iCur, lane, S);
    const int cc = lane & 15, g = lane >> 4;
    const int soff = cc * 16 + g * 4;
    float* op = out + (size_t)p * COUT;
    const short8 a = pack_bf8(S.wf);
    #pragma unroll
    for (int t = 0; t < 4; ++t) {
      const short8 bb = pack_bf8(S.bg[t]);
      f32x4 acc = {0.f, 0.f, 0.f, 0.f};
      acc = __builtin_amdgcn_mfma_f32_16x16x32_bf16(a, bb, acc, 0, 0, 0);
      __builtin_nontemporal_store(acc, reinterpret_cast<f32x4*>(op + soff + t * 256));
    }
    {
      const short8 bb = pack_bf8(S.ad);
      f32x4 acc = {0.f, 0.f, 0.f, 0.f};
      acc = __builtin_amdgcn_mfma_f32_16x16x32_bf16(a, bb, acc, 0, 0, 0);
      if (cc < 3)
        __builtin_nontemporal_store(acc, reinterpret_cast<f32x4*>(op + soff + 1024));
    }
    #pragma unroll
    for (int j = 0; j < 16; ++j) iCur.v[j] = iNext.v[j];
  }
}

extern "C" void kernel_launch(void* const* d_in, const int* in_sizes, int n_in,
                              void* d_out, int out_size, void* d_ws, size_t ws_size,
                              hipStream_t stream) {
  const float* feat = (const float*)d_in[0];
  const int*   inds = (const int*)d_in[1];
  const float* wnet = (const float*)d_in[2];
  const float* addf = (const float*)d_in[3];
  float* outp = (float*)d_out;

  dim3 grid(4096), block(256);
  if (ws_size >= SINK_OFF_D + (size_t)16384 * 4) {
    unsigned short* tbl = (unsigned short*)d_ws;
    float* sinkA = (float*)((char*)d_ws + SINK_OFF_A);
    float* sinkD = (float*)((char*)d_ws + SINK_OFF_D);
    hipLaunchKernelGGL(cvt_feat_bf16, dim3(2048), dim3(256), 0, stream, feat, tbl);
    hipLaunchKernelGGL(abl_loads,     grid, block, 0, stream, tbl, inds, wnet, addf, sinkA);
    hipLaunchKernelGGL(abl_store,     grid, block, 0, stream, outp);
    hipLaunchKernelGGL(abl_vecgather, grid, block, 0, stream, tbl, inds, sinkD);
    hipLaunchKernelGGL(pconv16,       grid, block, 0, stream, tbl, inds, wnet, addf, outp);
    hipLaunchKernelGGL(pconv9_tbl,    grid, block, 0, stream, tbl, inds, wnet, addf, outp);
  } else {
    hipLaunchKernelGGL(pconv9_f32, grid, block, 0, stream,
                       feat, inds, wnet, addf, outp);
  }
}

// Round 10
// 166.137 us; speedup vs baseline: 14.9574x; 14.9574x over previous
//
#include <hip/hip_runtime.h>
#include <cstdint>
#include <cstddef>

// PConv, round 10: VMEM-instruction-count attack.
// R8/R9 evidence: fused kernel 152us with no saturated pipe; loads-only and
// stores-only each <=102us; ~80 narrow half-wave VMEM instr per m ~= 11 cyc each
// -> TA/address-path instruction bound. Fix: K=16-exact mfma_f32_16x16x16bf16_1k
// so ALL 64 lanes carry real data; 16 full-wave 2B gathers + 4 wn + 4 ad + 5
// stores ~= 29 VMEM instr/m. No LDS, no fences, no dynamic register indexing
// (R9's abl_vecgather/pconv16 LDS-promotion artifact: rule #20).
//   A-frag: lane(w=l&15, g=l>>4) holds wn[4g+j][w], j=0..3
//   B-frag: lane(cc,g)          holds tbl[idx[4g+j]][16t+cc]
//   D:      lane(cc,g) reg r -> out[(16t+cc)*16 + 4g+r]  (validated R5/R7 layout)

namespace {
constexpr int B_   = 2;
constexpr int N_   = 50000;
constexpr int M_   = 50000;
constexpr int KNB  = 16;
constexpr int CIN  = 64;
constexpr int COUT = 67 * 16;      // 1072
constexpr int PAIRS = B_ * M_;     // 100000
constexpr int FELEMS = B_ * N_ * CIN;   // 6,400,000
}

typedef unsigned int u32;
typedef float  f32x4   __attribute__((ext_vector_type(4)));
typedef short  short8  __attribute__((ext_vector_type(8)));
typedef short  short4v __attribute__((ext_vector_type(4)));
typedef u32    u32x4   __attribute__((ext_vector_type(4)));
typedef u32    u32x2   __attribute__((ext_vector_type(2)));

struct IdxS   { int v[16]; };                      // wave-uniform (SGPRs)
struct StageF { float bg[4][8]; float ad[8]; float wf[8]; };

static __device__ __forceinline__ short8 pack_bf8(const float* x) {
  u32x4 w;
  #pragma unroll
  for (int q = 0; q < 4; ++q)
    w[q] = __builtin_amdgcn_perm(__builtin_bit_cast(u32, x[2*q+1]),
                                 __builtin_bit_cast(u32, x[2*q]),
                                 0x07060302u);
  return __builtin_bit_cast(short8, w);
}

static __device__ __forceinline__ short4v pack_bf4(const float* x) {
  u32x2 w;
  #pragma unroll
  for (int q = 0; q < 2; ++q)
    w[q] = __builtin_amdgcn_perm(__builtin_bit_cast(u32, x[2*q+1]),
                                 __builtin_bit_cast(u32, x[2*q]),
                                 0x07060302u);
  return __builtin_bit_cast(short4v, w);
}

static __device__ __forceinline__ u32 bfrne(float x) {
  u32 u = __builtin_bit_cast(u32, x);
  return (u + 0x7FFFu + ((u >> 16) & 1u)) >> 16;
}

// ---------------- pre-pass: f32 -> bf16 (RNE) table ----------------
__global__ __launch_bounds__(256)
void cvt_feat_bf16(const float* __restrict__ src, unsigned short* __restrict__ dst) {
  const int n4 = FELEMS / 4;
  int i = blockIdx.x * blockDim.x + threadIdx.x;
  const int stride = gridDim.x * blockDim.x;
  const f32x4* s4 = reinterpret_cast<const f32x4*>(src);
  for (; i < n4; i += stride) {
    f32x4 v = s4[i];
    u32x2 w;
    w[0] = bfrne(v[0]) | (bfrne(v[1]) << 16);
    w[1] = bfrne(v[2]) | (bfrne(v[3]) << 16);
    *reinterpret_cast<u32x2*>(dst + 4 * (size_t)i) = w;
  }
}

static __device__ __forceinline__ void load_idx(const int* __restrict__ idxp, IdxS& r) {
  #pragma unroll
  for (int j = 0; j < 16; ++j)
    r.v[j] = __builtin_amdgcn_readfirstlane(idxp[j]);
}

#if __has_builtin(__builtin_amdgcn_mfma_f32_16x16x16bf16_1k)

// ---------------- main: all-lane K=16 MFMA, 29 VMEM instr per m ----------------
__global__ __launch_bounds__(256, 8)
void pconv10(const unsigned short* __restrict__ tbl, const int* __restrict__ inds,
             const float* __restrict__ wnet, const float* __restrict__ addf,
             float* __restrict__ out)
{
  const int lane = threadIdx.x & 63;
  const int cc = lane & 15, g = lane >> 4;
  const int g1 = g & 1, g2 = g >> 1;
  const int gw = __builtin_amdgcn_readfirstlane(
      (int)((blockIdx.x * blockDim.x + threadIdx.x) >> 6));
  const int nw = (int)((gridDim.x * blockDim.x) >> 6);
  if (gw >= PAIRS) return;

  IdxS iCur, iNext;
  load_idx(inds + (size_t)gw * KNB, iCur);

  for (int p = gw; p < PAIRS; p += nw) {
    const int pn = (p + nw < PAIRS) ? (p + nw) : gw;   // clamped idx prefetch
    load_idx(inds + (size_t)pn * KNB, iNext);

    const int b = (p >= M_) ? 1 : 0;
    const unsigned short* __restrict__ fb  = tbl + (size_t)b * N_ * CIN;
    const float* __restrict__ wnp = wnet + (size_t)p * 256;
    const float* __restrict__ adp = addf + (size_t)p * 48;

    // per-lane neighbor rows for k = 4g+j, via STATIC-indexed cndmask selects
    int row[4];
    #pragma unroll
    for (int j = 0; j < 4; ++j) {
      const int ra = g1 ? iCur.v[4 + j]  : iCur.v[j];
      const int rb = g1 ? iCur.v[12 + j] : iCur.v[8 + j];
      row[j] = g2 ? rb : ra;
    }

    // gather: 16 full-wave ushort loads (4 random rows x 32B contiguous each)
    u32 bg[4][4];
    #pragma unroll
    for (int j = 0; j < 4; ++j) {
      const unsigned short* __restrict__ rp = fb + (((u32)row[j]) << 6) + (u32)cc;
      #pragma unroll
      for (int t = 0; t < 4; ++t)
        bg[t][j] = rp[t * 16];                   // imm-offset siblings
    }

    // wn: 4 full-wave f32 loads (contiguous 1KB total)
    float wf[4];
    const float* __restrict__ wp = wnp + g * 64 + cc;
    #pragma unroll
    for (int j = 0; j < 4; ++j)
      wf[j] = __builtin_nontemporal_load(wp + j * 16);

    // ad: 4 loads, 12 active lanes
    float ad[4];
    const float* __restrict__ ap = adp + g * 12 + cc;
    #pragma unroll
    for (int j = 0; j < 4; ++j)
      ad[j] = (cc < 3) ? __builtin_nontemporal_load(ap + j * 3) : 0.f;

    // fragments
    const short4v a = pack_bf4(wf);
    float* __restrict__ op = out + (size_t)p * COUT;
    const int soff = cc * 16 + g * 4;

    #pragma unroll
    for (int t = 0; t < 4; ++t) {
      u32x2 w;
      w[0] = bg[t][0] | (bg[t][1] << 16);
      w[1] = bg[t][2] | (bg[t][3] << 16);
      const short4v bb = __builtin_bit_cast(short4v, w);
      f32x4 acc = {0.f, 0.f, 0.f, 0.f};
      acc = __builtin_amdgcn_mfma_f32_16x16x16bf16_1k(a, bb, acc, 0, 0, 0);
      __builtin_nontemporal_store(acc, reinterpret_cast<f32x4*>(op + soff + t * 256));
    }
    {
      const short4v bb = pack_bf4(ad);
      f32x4 acc = {0.f, 0.f, 0.f, 0.f};
      acc = __builtin_amdgcn_mfma_f32_16x16x16bf16_1k(a, bb, acc, 0, 0, 0);
      if (cc < 3)
        __builtin_nontemporal_store(acc, reinterpret_cast<f32x4*>(op + soff + 1024));
    }

    #pragma unroll
    for (int j = 0; j < 16; ++j) iCur.v[j] = iNext.v[j];
  }
}

#else  // builtin absent: proven R7 structure (half-wave x32 MFMA)

struct StageT { unsigned short bg[4][8]; float ad[8]; float wf[8]; };

static __device__ __forceinline__ void load_stage_t(const unsigned short* __restrict__ fb,
                                                    const float* __restrict__ wnp,
                                                    const float* __restrict__ adp,
                                                    const IdxS& I, int lane, StageT& S) {
  const int cc = lane & 15;
  if (lane < 32) {
    const int hi = lane >> 4;
    int rows[8];
    #pragma unroll
    for (int j = 0; j < 8; ++j) rows[j] = hi ? I.v[j + 8] : I.v[j];
    #pragma unroll
    for (int j = 0; j < 8; ++j) {
      const u32 rb = ((u32)rows[j]) << 6;
      #pragma unroll
      for (int t = 0; t < 4; ++t)
        S.bg[t][j] = fb[rb + (u32)(t * 16 + cc)];
    }
    const u32 woff = (hi ? 128u : 0u) + (u32)cc;
    #pragma unroll
    for (int j = 0; j < 8; ++j)
      S.wf[j] = __builtin_nontemporal_load(wnp + woff + j * 16);
    if (cc < 3) {
      const u32 aoff = (hi ? 24u : 0u) + (u32)cc;
      #pragma unroll
      for (int j = 0; j < 8; ++j)
        S.ad[j] = __builtin_nontemporal_load(adp + aoff + j * 3);
    }
  }
}

__global__ __launch_bounds__(256, 4)
void pconv10(const unsigned short* __restrict__ tbl, const int* __restrict__ inds,
             const float* __restrict__ wnet, const float* __restrict__ addf,
             float* __restrict__ out)
{
  const int lane = threadIdx.x & 63;
  const int gw = __builtin_amdgcn_readfirstlane(
      (int)((blockIdx.x * blockDim.x + threadIdx.x) >> 6));
  const int nw = (int)((gridDim.x * blockDim.x) >> 6);
  if (gw >= PAIRS) return;

  IdxS iCur, iNext;
  load_idx(inds + (size_t)gw * KNB, iCur);
  for (int p = gw; p < PAIRS; p += nw) {
    const int pn = (p + nw < PAIRS) ? (p + nw) : gw;
    load_idx(inds + (size_t)pn * KNB, iNext);
    const int b = (p >= M_) ? 1 : 0;
    StageT S = {};
    load_stage_t(tbl + (size_t)b * N_ * CIN, wnet + (size_t)p * 256,
                 addf + (size_t)p * 48, iCur, lane, S);
    const int cc = lane & 15, g = lane >> 4;
    const int soff = cc * 16 + g * 4;
    float* op = out + (size_t)p * COUT;
    const short8 a = pack_bf8(S.wf);
    #pragma unroll
    for (int t = 0; t < 4; ++t) {
      short8 bb;
      #pragma unroll
      for (int j = 0; j < 8; ++j) bb[j] = (short)S.bg[t][j];
      f32x4 acc = {0.f, 0.f, 0.f, 0.f};
      acc = __builtin_amdgcn_mfma_f32_16x16x32_bf16(a, bb, acc, 0, 0, 0);
      __builtin_nontemporal_store(acc, reinterpret_cast<f32x4*>(op + soff + t * 256));
    }
    {
      const short8 bb = pack_bf8(S.ad);
      f32x4 acc = {0.f, 0.f, 0.f, 0.f};
      acc = __builtin_amdgcn_mfma_f32_16x16x32_bf16(a, bb, acc, 0, 0, 0);
      if (cc < 3)
        __builtin_nontemporal_store(acc, reinterpret_cast<f32x4*>(op + soff + 1024));
    }
    #pragma unroll
    for (int j = 0; j < 16; ++j) iCur.v[j] = iNext.v[j];
  }
}

#endif  // __has_builtin

// ---------------- fallback (ws too small): proven R7-f32 single pass ----------------
static __device__ __forceinline__ void load_stage_f(const float* __restrict__ fb,
                                                    const float* __restrict__ wnp,
                                                    const float* __restrict__ adp,
                                                    const IdxS& I, int lane, StageF& S) {
  const int cc = lane & 15;
  if (lane < 32) {
    const int hi = lane >> 4;
    int rows[8];
    #pragma unroll
    for (int j = 0; j < 8; ++j) rows[j] = hi ? I.v[j + 8] : I.v[j];
    #pragma unroll
    for (int j = 0; j < 8; ++j) {
      const u32 rb = ((u32)rows[j]) << 6;
      #pragma unroll
      for (int t = 0; t < 4; ++t)
        S.bg[t][j] = fb[rb + (u32)(t * 16 + cc)];
    }
    const u32 woff = (hi ? 128u : 0u) + (u32)cc;
    #pragma unroll
    for (int j = 0; j < 8; ++j)
      S.wf[j] = __builtin_nontemporal_load(wnp + woff + j * 16);
    if (cc < 3) {
      const u32 aoff = (hi ? 24u : 0u) + (u32)cc;
      #pragma unroll
      for (int j = 0; j < 8; ++j)
        S.ad[j] = __builtin_nontemporal_load(adp + aoff + j * 3);
    }
  }
}

__global__ __launch_bounds__(256, 4)
void pconv10_f32(const float* __restrict__ feat, const int* __restrict__ inds,
                 const float* __restrict__ wnet, const float* __restrict__ addf,
                 float* __restrict__ out)
{
  const int lane = threadIdx.x & 63;
  const int gw = __builtin_amdgcn_readfirstlane(
      (int)((blockIdx.x * blockDim.x + threadIdx.x) >> 6));
  const int nw = (int)((gridDim.x * blockDim.x) >> 6);
  if (gw >= PAIRS) return;

  IdxS iCur, iNext;
  load_idx(inds + (size_t)gw * KNB, iCur);
  for (int p = gw; p < PAIRS; p += nw) {
    const int pn = (p + nw < PAIRS) ? (p + nw) : gw;
    load_idx(inds + (size_t)pn * KNB, iNext);
    const int b = (p >= M_) ? 1 : 0;
    StageF S = {};
    load_stage_f(feat + (size_t)b * N_ * CIN, wnet + (size_t)p * 256,
                 addf + (size_t)p * 48, iCur, lane, S);
    const int cc = lane & 15, g = lane >> 4;
    const int soff = cc * 16 + g * 4;
    float* op = out + (size_t)p * COUT;
    const short8 a = pack_bf8(S.wf);
    #pragma unroll
    for (int t = 0; t < 4; ++t) {
      const short8 bb = pack_bf8(S.bg[t]);
      f32x4 acc = {0.f, 0.f, 0.f, 0.f};
      acc = __builtin_amdgcn_mfma_f32_16x16x32_bf16(a, bb, acc, 0, 0, 0);
      __builtin_nontemporal_store(acc, reinterpret_cast<f32x4*>(op + soff + t * 256));
    }
    {
      const short8 bb = pack_bf8(S.ad);
      f32x4 acc = {0.f, 0.f, 0.f, 0.f};
      acc = __builtin_amdgcn_mfma_f32_16x16x32_bf16(a, bb, acc, 0, 0, 0);
      if (cc < 3)
        __builtin_nontemporal_store(acc, reinterpret_cast<f32x4*>(op + soff + 1024));
    }
    #pragma unroll
    for (int j = 0; j < 16; ++j) iCur.v[j] = iNext.v[j];
  }
}

extern "C" void kernel_launch(void* const* d_in, const int* in_sizes, int n_in,
                              void* d_out, int out_size, void* d_ws, size_t ws_size,
                              hipStream_t stream) {
  const float* feat = (const float*)d_in[0];
  const int*   inds = (const int*)d_in[1];
  const float* wnet = (const float*)d_in[2];
  const float* addf = (const float*)d_in[3];
  float* outp = (float*)d_out;

  const size_t TBL_BYTES = (size_t)FELEMS * sizeof(unsigned short);  // 12.8 MB

  dim3 grid(4096), block(256);
  if (ws_size >= TBL_BYTES) {
    unsigned short* tbl = (unsigned short*)d_ws;
    hipLaunchKernelGGL(cvt_feat_bf16, dim3(2048), dim3(256), 0, stream, feat, tbl);
    hipLaunchKernelGGL(pconv10, grid, block, 0, stream, tbl, inds, wnet, addf, outp);
  } else {
    hipLaunchKernelGGL(pconv10_f32, grid, block, 0, stream,
                       feat, inds, wnet, addf, outp);
  }
}

// Round 11
// 158.643 us; speedup vs baseline: 15.6640x; 1.0472x over previous
//
#include <hip/hip_runtime.h>
#include <cstdint>
#include <cstddef>

// PConv, round 11: 3-deep register pipeline on the validated all-lane
// 16x16x16bf16_1k body. Concurrency test: 16 waves/CU x 3 in-flight
// iterations = 12 dependent chains per SIMD (prev rounds: 5-8).
// No LDS, no fences, static indexing only (rule #20), no spill by design.
//   A-frag: lane(w=l&15, g=l>>4) holds wn[4g+j][w], j=0..3
//   B-frag: lane(cc,g)          holds tbl[idx[4g+j]][16t+cc]
//   D:      lane(cc,g) reg r -> out[(16t+cc)*16 + 4g+r]  (validated R10)

namespace {
constexpr int B_   = 2;
constexpr int N_   = 50000;
constexpr int M_   = 50000;
constexpr int KNB  = 16;
constexpr int CIN  = 64;
constexpr int COUT = 67 * 16;      // 1072
constexpr int PAIRS = B_ * M_;     // 100000
constexpr int FELEMS = B_ * N_ * CIN;   // 6,400,000
}

typedef unsigned int u32;
typedef float  f32x4   __attribute__((ext_vector_type(4)));
typedef short  short8  __attribute__((ext_vector_type(8)));
typedef short  short4v __attribute__((ext_vector_type(4)));
typedef u32    u32x4   __attribute__((ext_vector_type(4)));
typedef u32    u32x2   __attribute__((ext_vector_type(2)));

struct IdxS   { int v[16]; };                       // wave-uniform (SGPRs)
struct StageG { u32 bg[4][4]; float wf[4]; float ad[4]; };   // ~24 VGPR
struct StageF { float bg[4][8]; float ad[8]; float wf[8]; };

static __device__ __forceinline__ short8 pack_bf8(const float* x) {
  u32x4 w;
  #pragma unroll
  for (int q = 0; q < 4; ++q)
    w[q] = __builtin_amdgcn_perm(__builtin_bit_cast(u32, x[2*q+1]),
                                 __builtin_bit_cast(u32, x[2*q]),
                                 0x07060302u);
  return __builtin_bit_cast(short8, w);
}

static __device__ __forceinline__ short4v pack_bf4(const float* x) {
  u32x2 w;
  #pragma unroll
  for (int q = 0; q < 2; ++q)
    w[q] = __builtin_amdgcn_perm(__builtin_bit_cast(u32, x[2*q+1]),
                                 __builtin_bit_cast(u32, x[2*q]),
                                 0x07060302u);
  return __builtin_bit_cast(short4v, w);
}

static __device__ __forceinline__ u32 bfrne(float x) {
  u32 u = __builtin_bit_cast(u32, x);
  return (u + 0x7FFFu + ((u >> 16) & 1u)) >> 16;
}

// ---------------- pre-pass: f32 -> bf16 (RNE) table ----------------
__global__ __launch_bounds__(256)
void cvt_feat_bf16(const float* __restrict__ src, unsigned short* __restrict__ dst) {
  const int n4 = FELEMS / 4;
  int i = blockIdx.x * blockDim.x + threadIdx.x;
  const int stride = gridDim.x * blockDim.x;
  const f32x4* s4 = reinterpret_cast<const f32x4*>(src);
  for (; i < n4; i += stride) {
    f32x4 v = s4[i];
    u32x2 w;
    w[0] = bfrne(v[0]) | (bfrne(v[1]) << 16);
    w[1] = bfrne(v[2]) | (bfrne(v[3]) << 16);
    *reinterpret_cast<u32x2*>(dst + 4 * (size_t)i) = w;
  }
}

static __device__ __forceinline__ void load_idx(const int* __restrict__ idxp, IdxS& r) {
  #pragma unroll
  for (int j = 0; j < 16; ++j)
    r.v[j] = __builtin_amdgcn_readfirstlane(idxp[j]);
}

#if __has_builtin(__builtin_amdgcn_mfma_f32_16x16x16bf16_1k)

// issue one iteration's 24 loads (gather 16 + wn 4 + ad 4), all full-wave
static __device__ __forceinline__ void issue_loads(const unsigned short* __restrict__ tbl,
                                                   const float* __restrict__ wnet,
                                                   const float* __restrict__ addf,
                                                   int q, const IdxS& I,
                                                   int cc, int g1, int g2, int g,
                                                   StageG& S) {
  const unsigned short* __restrict__ fb =
      tbl + ((q >= M_) ? (size_t)N_ * CIN : 0);
  const float* __restrict__ wnp = wnet + (size_t)q * 256;
  const float* __restrict__ adp = addf + (size_t)q * 48;

  int row[4];
  #pragma unroll
  for (int j = 0; j < 4; ++j) {                 // static-indexed cndmask selects
    const int ra = g1 ? I.v[4 + j]  : I.v[j];
    const int rb = g1 ? I.v[12 + j] : I.v[8 + j];
    row[j] = g2 ? rb : ra;
  }
  #pragma unroll
  for (int j = 0; j < 4; ++j) {
    const unsigned short* __restrict__ rp = fb + (((u32)row[j]) << 6) + (u32)cc;
    #pragma unroll
    for (int t = 0; t < 4; ++t)
      S.bg[t][j] = rp[t * 16];                  // ushort -> u32 zero-extend
  }
  const float* __restrict__ wp = wnp + g * 64 + cc;
  #pragma unroll
  for (int j = 0; j < 4; ++j)
    S.wf[j] = __builtin_nontemporal_load(wp + j * 16);
  const float* __restrict__ ap = adp + g * 12 + cc;
  #pragma unroll
  for (int j = 0; j < 4; ++j)
    S.ad[j] = (cc < 3) ? __builtin_nontemporal_load(ap + j * 3) : 0.f;
}

static __device__ __forceinline__ void compute_store(const StageG& S,
                                                     float* __restrict__ op,
                                                     int cc, int g) {
  const int soff = cc * 16 + g * 4;
  const short4v a = pack_bf4(S.wf);
  #pragma unroll
  for (int t = 0; t < 4; ++t) {
    u32x2 w;
    w[0] = S.bg[t][0] | (S.bg[t][1] << 16);
    w[1] = S.bg[t][2] | (S.bg[t][3] << 16);
    const short4v bb = __builtin_bit_cast(short4v, w);
    f32x4 acc = {0.f, 0.f, 0.f, 0.f};
    acc = __builtin_amdgcn_mfma_f32_16x16x16bf16_1k(a, bb, acc, 0, 0, 0);
    __builtin_nontemporal_store(acc, reinterpret_cast<f32x4*>(op + soff + t * 256));
  }
  {
    const short4v bb = pack_bf4(S.ad);
    f32x4 acc = {0.f, 0.f, 0.f, 0.f};
    acc = __builtin_amdgcn_mfma_f32_16x16x16bf16_1k(a, bb, acc, 0, 0, 0);
    if (cc < 3)
      __builtin_nontemporal_store(acc, reinterpret_cast<f32x4*>(op + soff + 1024));
  }
}

__global__ __launch_bounds__(256, 4)
void pconv11(const unsigned short* __restrict__ tbl, const int* __restrict__ inds,
             const float* __restrict__ wnet, const float* __restrict__ addf,
             float* __restrict__ out)
{
  const int lane = threadIdx.x & 63;
  const int cc = lane & 15, g = lane >> 4;
  const int g1 = g & 1, g2 = g >> 1;
  const int gw = __builtin_amdgcn_readfirstlane(
      (int)((blockIdx.x * blockDim.x + threadIdx.x) >> 6));
  const int nw = (int)((gridDim.x * blockDim.x) >> 6);
  if (gw >= PAIRS) return;

  IdxS iA, iB, iC;
  StageG sA, sB, sC;
  int p = gw;

  // prologue: idx 3 ahead, loads 2 ahead
  load_idx(inds + (size_t)p * KNB, iA);
  { const int q = (p + nw < PAIRS) ? (p + nw) : gw;
    load_idx(inds + (size_t)q * KNB, iB); }
  { const int q = (p + 2 * nw < PAIRS) ? (p + 2 * nw) : gw;
    load_idx(inds + (size_t)q * KNB, iC); }
  issue_loads(tbl, wnet, addf, p, iA, cc, g1, g2, g, sA);
  { const int q = (p + nw < PAIRS) ? (p + nw) : gw;
    issue_loads(tbl, wnet, addf, q, iB, cc, g1, g2, g, sB); }

  // 3-phase rotation: consume X(p); issue loads(p+2nw) into free stage;
  // refill the idx slot just consumed with idx(p+3nw).
  while (true) {
    { // phase A: consume sA; free stage = sC (uses iC); refill iA
      const int q2 = (p + 2 * nw < PAIRS) ? (p + 2 * nw) : gw;
      issue_loads(tbl, wnet, addf, q2, iC, cc, g1, g2, g, sC);
      const int q3 = (p + 3 * nw < PAIRS) ? (p + 3 * nw) : gw;
      load_idx(inds + (size_t)q3 * KNB, iA);
      compute_store(sA, out + (size_t)p * COUT, cc, g);
      p += nw; if (p >= PAIRS) break;
    }
    { // phase B: consume sB; free stage = sA (uses iA); refill iB
      const int q2 = (p + 2 * nw < PAIRS) ? (p + 2 * nw) : gw;
      issue_loads(tbl, wnet, addf, q2, iA, cc, g1, g2, g, sA);
      const int q3 = (p + 3 * nw < PAIRS) ? (p + 3 * nw) : gw;
      load_idx(inds + (size_t)q3 * KNB, iB);
      compute_store(sB, out + (size_t)p * COUT, cc, g);
      p += nw; if (p >= PAIRS) break;
    }
    { // phase C: consume sC; free stage = sB (uses iB); refill iC
      const int q2 = (p + 2 * nw < PAIRS) ? (p + 2 * nw) : gw;
      issue_loads(tbl, wnet, addf, q2, iB, cc, g1, g2, g, sB);
      const int q3 = (p + 3 * nw < PAIRS) ? (p + 3 * nw) : gw;
      load_idx(inds + (size_t)q3 * KNB, iC);
      compute_store(sC, out + (size_t)p * COUT, cc, g);
      p += nw; if (p >= PAIRS) break;
    }
  }
}

#else  // builtin absent: proven R7 structure

struct StageT { unsigned short bg[4][8]; float ad[8]; float wf[8]; };

static __device__ __forceinline__ void load_stage_t(const unsigned short* __restrict__ fb,
                                                    const float* __restrict__ wnp,
                                                    const float* __restrict__ adp,
                                                    const IdxS& I, int lane, StageT& S) {
  const int cc = lane & 15;
  if (lane < 32) {
    const int hi = lane >> 4;
    int rows[8];
    #pragma unroll
    for (int j = 0; j < 8; ++j) rows[j] = hi ? I.v[j + 8] : I.v[j];
    #pragma unroll
    for (int j = 0; j < 8; ++j) {
      const u32 rb = ((u32)rows[j]) << 6;
      #pragma unroll
      for (int t = 0; t < 4; ++t)
        S.bg[t][j] = fb[rb + (u32)(t * 16 + cc)];
    }
    const u32 woff = (hi ? 128u : 0u) + (u32)cc;
    #pragma unroll
    for (int j = 0; j < 8; ++j)
      S.wf[j] = __builtin_nontemporal_load(wnp + woff + j * 16);
    if (cc < 3) {
      const u32 aoff = (hi ? 24u : 0u) + (u32)cc;
      #pragma unroll
      for (int j = 0; j < 8; ++j)
        S.ad[j] = __builtin_nontemporal_load(adp + aoff + j * 3);
    }
  }
}

__global__ __launch_bounds__(256, 4)
void pconv11(const unsigned short* __restrict__ tbl, const int* __restrict__ inds,
             const float* __restrict__ wnet, const float* __restrict__ addf,
             float* __restrict__ out)
{
  const int lane = threadIdx.x & 63;
  const int gw = __builtin_amdgcn_readfirstlane(
      (int)((blockIdx.x * blockDim.x + threadIdx.x) >> 6));
  const int nw = (int)((gridDim.x * blockDim.x) >> 6);
  if (gw >= PAIRS) return;

  IdxS iCur, iNext;
  load_idx(inds + (size_t)gw * KNB, iCur);
  for (int p = gw; p < PAIRS; p += nw) {
    const int pn = (p + nw < PAIRS) ? (p + nw) : gw;
    load_idx(inds + (size_t)pn * KNB, iNext);
    const int b = (p >= M_) ? 1 : 0;
    StageT S = {};
    load_stage_t(tbl + (size_t)b * N_ * CIN, wnet + (size_t)p * 256,
                 addf + (size_t)p * 48, iCur, lane, S);
    const int cc = lane & 15, g = lane >> 4;
    const int soff = cc * 16 + g * 4;
    float* op = out + (size_t)p * COUT;
    const short8 a = pack_bf8(S.wf);
    #pragma unroll
    for (int t = 0; t < 4; ++t) {
      short8 bb;
      #pragma unroll
      for (int j = 0; j < 8; ++j) bb[j] = (short)S.bg[t][j];
      f32x4 acc = {0.f, 0.f, 0.f, 0.f};
      acc = __builtin_amdgcn_mfma_f32_16x16x32_bf16(a, bb, acc, 0, 0, 0);
      __builtin_nontemporal_store(acc, reinterpret_cast<f32x4*>(op + soff + t * 256));
    }
    {
      const short8 bb = pack_bf8(S.ad);
      f32x4 acc = {0.f, 0.f, 0.f, 0.f};
      acc = __builtin_amdgcn_mfma_f32_16x16x32_bf16(a, bb, acc, 0, 0, 0);
      if (cc < 3)
        __builtin_nontemporal_store(acc, reinterpret_cast<f32x4*>(op + soff + 1024));
    }
    #pragma unroll
    for (int j = 0; j < 16; ++j) iCur.v[j] = iNext.v[j];
  }
}

#endif  // __has_builtin

// ---------------- fallback (ws too small): proven R7-f32 single pass ----------------
static __device__ __forceinline__ void load_stage_f(const float* __restrict__ fb,
                                                    const float* __restrict__ wnp,
                                                    const float* __restrict__ adp,
                                                    const IdxS& I, int lane, StageF& S) {
  const int cc = lane & 15;
  if (lane < 32) {
    const int hi = lane >> 4;
    int rows[8];
    #pragma unroll
    for (int j = 0; j < 8; ++j) rows[j] = hi ? I.v[j + 8] : I.v[j];
    #pragma unroll
    for (int j = 0; j < 8; ++j) {
      const u32 rb = ((u32)rows[j]) << 6;
      #pragma unroll
      for (int t = 0; t < 4; ++t)
        S.bg[t][j] = fb[rb + (u32)(t * 16 + cc)];
    }
    const u32 woff = (hi ? 128u : 0u) + (u32)cc;
    #pragma unroll
    for (int j = 0; j < 8; ++j)
      S.wf[j] = __builtin_nontemporal_load(wnp + woff + j * 16);
    if (cc < 3) {
      const u32 aoff = (hi ? 24u : 0u) + (u32)cc;
      #pragma unroll
      for (int j = 0; j < 8; ++j)
        S.ad[j] = __builtin_nontemporal_load(adp + aoff + j * 3);
    }
  }
}

__global__ __launch_bounds__(256, 4)
void pconv11_f32(const float* __restrict__ feat, const int* __restrict__ inds,
                 const float* __restrict__ wnet, const float* __restrict__ addf,
                 float* __restrict__ out)
{
  const int lane = threadIdx.x & 63;
  const int gw = __builtin_amdgcn_readfirstlane(
      (int)((blockIdx.x * blockDim.x + threadIdx.x) >> 6));
  const int nw = (int)((gridDim.x * blockDim.x) >> 6);
  if (gw >= PAIRS) return;

  IdxS iCur, iNext;
  load_idx(inds + (size_t)gw * KNB, iCur);
  for (int p = gw; p < PAIRS; p += nw) {
    const int pn = (p + nw < PAIRS) ? (p + nw) : gw;
    load_idx(inds + (size_t)pn * KNB, iNext);
    const int b = (p >= M_) ? 1 : 0;
    StageF S = {};
    load_stage_f(feat + (size_t)b * N_ * CIN, wnet + (size_t)p * 256,
                 addf + (size_t)p * 48, iCur, lane, S);
    const int cc = lane & 15, g = lane >> 4;
    const int soff = cc * 16 + g * 4;
    float* op = out + (size_t)p * COUT;
    const short8 a = pack_bf8(S.wf);
    #pragma unroll
    for (int t = 0; t < 4; ++t) {
      const short8 bb = pack_bf8(S.bg[t]);
      f32x4 acc = {0.f, 0.f, 0.f, 0.f};
      acc = __builtin_amdgcn_mfma_f32_16x16x32_bf16(a, bb, acc, 0, 0, 0);
      __builtin_nontemporal_store(acc, reinterpret_cast<f32x4*>(op + soff + t * 256));
    }
    {
      const short8 bb = pack_bf8(S.ad);
      f32x4 acc = {0.f, 0.f, 0.f, 0.f};
      acc = __builtin_amdgcn_mfma_f32_16x16x32_bf16(a, bb, acc, 0, 0, 0);
      if (cc < 3)
        __builtin_nontemporal_store(acc, reinterpret_cast<f32x4*>(op + soff + 1024));
    }
    #pragma unroll
    for (int j = 0; j < 16; ++j) iCur.v[j] = iNext.v[j];
  }
}

extern "C" void kernel_launch(void* const* d_in, const int* in_sizes, int n_in,
                              void* d_out, int out_size, void* d_ws, size_t ws_size,
                              hipStream_t stream) {
  const float* feat = (const float*)d_in[0];
  const int*   inds = (const int*)d_in[1];
  const float* wnet = (const float*)d_in[2];
  const float* addf = (const float*)d_in[3];
  float* outp = (float*)d_out;

  const size_t TBL_BYTES = (size_t)FELEMS * sizeof(unsigned short);  // 12.8 MB

  dim3 grid(4096), block(256);
  if (ws_size >= TBL_BYTES) {
    unsigned short* tbl = (unsigned short*)d_ws;
    hipLaunchKernelGGL(cvt_feat_bf16, dim3(2048), dim3(256), 0, stream, feat, tbl);
    hipLaunchKernelGGL(pconv11, grid, block, 0, stream, tbl, inds, wnet, addf, outp);
  } else {
    hipLaunchKernelGGL(pconv11_f32, grid, block, 0, stream,
                       feat, inds, wnet, addf, outp);
  }
}

// Round 12
// 153.306 us; speedup vs baseline: 16.2093x; 1.0348x over previous
//
#include <hip/hip_runtime.h>
#include <cstdint>
#include <cstddef>

// PConv, round 12: 4-deep register pipeline (16 chains/SIMD) + grid 1024
// (4 blocks/CU resident, ~24 iters/wave -> prologue amortized 33%->12%).
// Validated all-lane 16x16x16bf16_1k body; no LDS, no fences, static
// indexing only (rule #20); 4 x 24-VGPR stages fit the (256,4) 128-VGPR cap.
//   A-frag: lane(w=l&15, g=l>>4) holds wn[4g+j][w], j=0..3
//   B-frag: lane(cc,g)          holds tbl[idx[4g+j]][16t+cc]
//   D:      lane(cc,g) reg r -> out[(16t+cc)*16 + 4g+r]  (validated R10/R11)

namespace {
constexpr int B_   = 2;
constexpr int N_   = 50000;
constexpr int M_   = 50000;
constexpr int KNB  = 16;
constexpr int CIN  = 64;
constexpr int COUT = 67 * 16;      // 1072
constexpr int PAIRS = B_ * M_;     // 100000
constexpr int FELEMS = B_ * N_ * CIN;   // 6,400,000
}

typedef unsigned int u32;
typedef float  f32x4   __attribute__((ext_vector_type(4)));
typedef short  short8  __attribute__((ext_vector_type(8)));
typedef short  short4v __attribute__((ext_vector_type(4)));
typedef u32    u32x4   __attribute__((ext_vector_type(4)));
typedef u32    u32x2   __attribute__((ext_vector_type(2)));

struct IdxS   { int v[16]; };                       // wave-uniform (SGPRs)
struct StageG { u32 bg[4][4]; float wf[4]; float ad[4]; };   // 24 VGPR
struct StageF { float bg[4][8]; float ad[8]; float wf[8]; };

static __device__ __forceinline__ short8 pack_bf8(const float* x) {
  u32x4 w;
  #pragma unroll
  for (int q = 0; q < 4; ++q)
    w[q] = __builtin_amdgcn_perm(__builtin_bit_cast(u32, x[2*q+1]),
                                 __builtin_bit_cast(u32, x[2*q]),
                                 0x07060302u);
  return __builtin_bit_cast(short8, w);
}

static __device__ __forceinline__ short4v pack_bf4(const float* x) {
  u32x2 w;
  #pragma unroll
  for (int q = 0; q < 2; ++q)
    w[q] = __builtin_amdgcn_perm(__builtin_bit_cast(u32, x[2*q+1]),
                                 __builtin_bit_cast(u32, x[2*q]),
                                 0x07060302u);
  return __builtin_bit_cast(short4v, w);
}

static __device__ __forceinline__ u32 bfrne(float x) {
  u32 u = __builtin_bit_cast(u32, x);
  return (u + 0x7FFFu + ((u >> 16) & 1u)) >> 16;
}

// ---------------- pre-pass: f32 -> bf16 (RNE) table ----------------
__global__ __launch_bounds__(256)
void cvt_feat_bf16(const float* __restrict__ src, unsigned short* __restrict__ dst) {
  const int n4 = FELEMS / 4;
  int i = blockIdx.x * blockDim.x + threadIdx.x;
  const int stride = gridDim.x * blockDim.x;
  const f32x4* s4 = reinterpret_cast<const f32x4*>(src);
  for (; i < n4; i += stride) {
    f32x4 v = s4[i];
    u32x2 w;
    w[0] = bfrne(v[0]) | (bfrne(v[1]) << 16);
    w[1] = bfrne(v[2]) | (bfrne(v[3]) << 16);
    *reinterpret_cast<u32x2*>(dst + 4 * (size_t)i) = w;
  }
}

static __device__ __forceinline__ void load_idx(const int* __restrict__ idxp, IdxS& r) {
  #pragma unroll
  for (int j = 0; j < 16; ++j)
    r.v[j] = __builtin_amdgcn_readfirstlane(idxp[j]);
}

#if __has_builtin(__builtin_amdgcn_mfma_f32_16x16x16bf16_1k)

// issue one iteration's 24 loads (gather 16 + wn 4 + ad 4), all full-wave
static __device__ __forceinline__ void issue_loads(const unsigned short* __restrict__ tbl,
                                                   const float* __restrict__ wnet,
                                                   const float* __restrict__ addf,
                                                   int q, const IdxS& I,
                                                   int cc, int g1, int g2, int g,
                                                   StageG& S) {
  const unsigned short* __restrict__ fb =
      tbl + ((q >= M_) ? (size_t)N_ * CIN : 0);
  const float* __restrict__ wnp = wnet + (size_t)q * 256;
  const float* __restrict__ adp = addf + (size_t)q * 48;

  int row[4];
  #pragma unroll
  for (int j = 0; j < 4; ++j) {                 // static-indexed cndmask selects
    const int ra = g1 ? I.v[4 + j]  : I.v[j];
    const int rb = g1 ? I.v[12 + j] : I.v[8 + j];
    row[j] = g2 ? rb : ra;
  }
  #pragma unroll
  for (int j = 0; j < 4; ++j) {
    const unsigned short* __restrict__ rp = fb + (((u32)row[j]) << 6) + (u32)cc;
    #pragma unroll
    for (int t = 0; t < 4; ++t)
      S.bg[t][j] = rp[t * 16];                  // ushort -> u32 zero-extend
  }
  const float* __restrict__ wp = wnp + g * 64 + cc;
  #pragma unroll
  for (int j = 0; j < 4; ++j)
    S.wf[j] = __builtin_nontemporal_load(wp + j * 16);
  const float* __restrict__ ap = adp + g * 12 + cc;
  #pragma unroll
  for (int j = 0; j < 4; ++j)
    S.ad[j] = (cc < 3) ? __builtin_nontemporal_load(ap + j * 3) : 0.f;
}

static __device__ __forceinline__ void compute_store(const StageG& S,
                                                     float* __restrict__ op,
                                                     int cc, int g) {
  const int soff = cc * 16 + g * 4;
  const short4v a = pack_bf4(S.wf);
  #pragma unroll
  for (int t = 0; t < 4; ++t) {
    u32x2 w;
    w[0] = S.bg[t][0] | (S.bg[t][1] << 16);
    w[1] = S.bg[t][2] | (S.bg[t][3] << 16);
    const short4v bb = __builtin_bit_cast(short4v, w);
    f32x4 acc = {0.f, 0.f, 0.f, 0.f};
    acc = __builtin_amdgcn_mfma_f32_16x16x16bf16_1k(a, bb, acc, 0, 0, 0);
    __builtin_nontemporal_store(acc, reinterpret_cast<f32x4*>(op + soff + t * 256));
  }
  {
    const short4v bb = pack_bf4(S.ad);
    f32x4 acc = {0.f, 0.f, 0.f, 0.f};
    acc = __builtin_amdgcn_mfma_f32_16x16x16bf16_1k(a, bb, acc, 0, 0, 0);
    if (cc < 3)
      __builtin_nontemporal_store(acc, reinterpret_cast<f32x4*>(op + soff + 1024));
  }
}

#define CLAMP_P(x) (((x) < PAIRS) ? (x) : gw)

__global__ __launch_bounds__(256, 4)
void pconv12(const unsigned short* __restrict__ tbl, const int* __restrict__ inds,
             const float* __restrict__ wnet, const float* __restrict__ addf,
             float* __restrict__ out)
{
  const int lane = threadIdx.x & 63;
  const int cc = lane & 15, g = lane >> 4;
  const int g1 = g & 1, g2 = g >> 1;
  const int gw = __builtin_amdgcn_readfirstlane(
      (int)((blockIdx.x * blockDim.x + threadIdx.x) >> 6));
  const int nw = (int)((gridDim.x * blockDim.x) >> 6);
  if (gw >= PAIRS) return;

  IdxS iA, iB, iC, iD;
  StageG sA, sB, sC, sD;
  int p = gw;

  // prologue: idx 4 ahead, loads 3 ahead
  load_idx(inds + (size_t)CLAMP_P(p) * KNB, iA);
  load_idx(inds + (size_t)CLAMP_P(p + nw) * KNB, iB);
  load_idx(inds + (size_t)CLAMP_P(p + 2 * nw) * KNB, iC);
  load_idx(inds + (size_t)CLAMP_P(p + 3 * nw) * KNB, iD);
  issue_loads(tbl, wnet, addf, CLAMP_P(p),          iA, cc, g1, g2, g, sA);
  issue_loads(tbl, wnet, addf, CLAMP_P(p + nw),     iB, cc, g1, g2, g, sB);
  issue_loads(tbl, wnet, addf, CLAMP_P(p + 2 * nw), iC, cc, g1, g2, g, sC);

  // 4-phase rotation: consume sX(p); issue loads(p+3nw) into the free stage
  // (3-back) using its idx; refill consumed slot's idx with idx(p+4nw).
  while (true) {
    { // phase A: consume sA; free = sD (iD); refill iA <- idx(p+4nw)
      issue_loads(tbl, wnet, addf, CLAMP_P(p + 3 * nw), iD, cc, g1, g2, g, sD);
      load_idx(inds + (size_t)CLAMP_P(p + 4 * nw) * KNB, iA);
      compute_store(sA, out + (size_t)p * COUT, cc, g);
      p += nw; if (p >= PAIRS) break;
    }
    { // phase B: consume sB; free = sA (iA); refill iB
      issue_loads(tbl, wnet, addf, CLAMP_P(p + 3 * nw), iA, cc, g1, g2, g, sA);
      load_idx(inds + (size_t)CLAMP_P(p + 4 * nw) * KNB, iB);
      compute_store(sB, out + (size_t)p * COUT, cc, g);
      p += nw; if (p >= PAIRS) break;
    }
    { // phase C: consume sC; free = sB (iB); refill iC
      issue_loads(tbl, wnet, addf, CLAMP_P(p + 3 * nw), iB, cc, g1, g2, g, sB);
      load_idx(inds + (size_t)CLAMP_P(p + 4 * nw) * KNB, iC);
      compute_store(sC, out + (size_t)p * COUT, cc, g);
      p += nw; if (p >= PAIRS) break;
    }
    { // phase D: consume sD; free = sC (iC); refill iD
      issue_loads(tbl, wnet, addf, CLAMP_P(p + 3 * nw), iC, cc, g1, g2, g, sC);
      load_idx(inds + (size_t)CLAMP_P(p + 4 * nw) * KNB, iD);
      compute_store(sD, out + (size_t)p * COUT, cc, g);
      p += nw; if (p >= PAIRS) break;
    }
  }
}

#undef CLAMP_P

#else  // builtin absent: proven R7 structure

struct StageT { unsigned short bg[4][8]; float ad[8]; float wf[8]; };

static __device__ __forceinline__ void load_stage_t(const unsigned short* __restrict__ fb,
                                                    const float* __restrict__ wnp,
                                                    const float* __restrict__ adp,
                                                    const IdxS& I, int lane, StageT& S) {
  const int cc = lane & 15;
  if (lane < 32) {
    const int hi = lane >> 4;
    int rows[8];
    #pragma unroll
    for (int j = 0; j < 8; ++j) rows[j] = hi ? I.v[j + 8] : I.v[j];
    #pragma unroll
    for (int j = 0; j < 8; ++j) {
      const u32 rb = ((u32)rows[j]) << 6;
      #pragma unroll
      for (int t = 0; t < 4; ++t)
        S.bg[t][j] = fb[rb + (u32)(t * 16 + cc)];
    }
    const u32 woff = (hi ? 128u : 0u) + (u32)cc;
    #pragma unroll
    for (int j = 0; j < 8; ++j)
      S.wf[j] = __builtin_nontemporal_load(wnp + woff + j * 16);
    if (cc < 3) {
      const u32 aoff = (hi ? 24u : 0u) + (u32)cc;
      #pragma unroll
      for (int j = 0; j < 8; ++j)
        S.ad[j] = __builtin_nontemporal_load(adp + aoff + j * 3);
    }
  }
}

__global__ __launch_bounds__(256, 4)
void pconv12(const unsigned short* __restrict__ tbl, const int* __restrict__ inds,
             const float* __restrict__ wnet, const float* __restrict__ addf,
             float* __restrict__ out)
{
  const int lane = threadIdx.x & 63;
  const int gw = __builtin_amdgcn_readfirstlane(
      (int)((blockIdx.x * blockDim.x + threadIdx.x) >> 6));
  const int nw = (int)((gridDim.x * blockDim.x) >> 6);
  if (gw >= PAIRS) return;

  IdxS iCur, iNext;
  load_idx(inds + (size_t)gw * KNB, iCur);
  for (int p = gw; p < PAIRS; p += nw) {
    const int pn = (p + nw < PAIRS) ? (p + nw) : gw;
    load_idx(inds + (size_t)pn * KNB, iNext);
    const int b = (p >= M_) ? 1 : 0;
    StageT S = {};
    load_stage_t(tbl + (size_t)b * N_ * CIN, wnet + (size_t)p * 256,
                 addf + (size_t)p * 48, iCur, lane, S);
    const int cc = lane & 15, g = lane >> 4;
    const int soff = cc * 16 + g * 4;
    float* op = out + (size_t)p * COUT;
    const short8 a = pack_bf8(S.wf);
    #pragma unroll
    for (int t = 0; t < 4; ++t) {
      short8 bb;
      #pragma unroll
      for (int j = 0; j < 8; ++j) bb[j] = (short)S.bg[t][j];
      f32x4 acc = {0.f, 0.f, 0.f, 0.f};
      acc = __builtin_amdgcn_mfma_f32_16x16x32_bf16(a, bb, acc, 0, 0, 0);
      __builtin_nontemporal_store(acc, reinterpret_cast<f32x4*>(op + soff + t * 256));
    }
    {
      const short8 bb = pack_bf8(S.ad);
      f32x4 acc = {0.f, 0.f, 0.f, 0.f};
      acc = __builtin_amdgcn_mfma_f32_16x16x32_bf16(a, bb, acc, 0, 0, 0);
      if (cc < 3)
        __builtin_nontemporal_store(acc, reinterpret_cast<f32x4*>(op + soff + 1024));
    }
    #pragma unroll
    for (int j = 0; j < 16; ++j) iCur.v[j] = iNext.v[j];
  }
}

#endif  // __has_builtin

// ---------------- fallback (ws too small): proven R7-f32 single pass ----------------
static __device__ __forceinline__ void load_stage_f(const float* __restrict__ fb,
                                                    const float* __restrict__ wnp,
                                                    const float* __restrict__ adp,
                                                    const IdxS& I, int lane, StageF& S) {
  const int cc = lane & 15;
  if (lane < 32) {
    const int hi = lane >> 4;
    int rows[8];
    #pragma unroll
    for (int j = 0; j < 8; ++j) rows[j] = hi ? I.v[j + 8] : I.v[j];
    #pragma unroll
    for (int j = 0; j < 8; ++j) {
      const u32 rb = ((u32)rows[j]) << 6;
      #pragma unroll
      for (int t = 0; t < 4; ++t)
        S.bg[t][j] = fb[rb + (u32)(t * 16 + cc)];
    }
    const u32 woff = (hi ? 128u : 0u) + (u32)cc;
    #pragma unroll
    for (int j = 0; j < 8; ++j)
      S.wf[j] = __builtin_nontemporal_load(wnp + woff + j * 16);
    if (cc < 3) {
      const u32 aoff = (hi ? 24u : 0u) + (u32)cc;
      #pragma unroll
      for (int j = 0; j < 8; ++j)
        S.ad[j] = __builtin_nontemporal_load(adp + aoff + j * 3);
    }
  }
}

__global__ __launch_bounds__(256, 4)
void pconv12_f32(const float* __restrict__ feat, const int* __restrict__ inds,
                 const float* __restrict__ wnet, const float* __restrict__ addf,
                 float* __restrict__ out)
{
  const int lane = threadIdx.x & 63;
  const int gw = __builtin_amdgcn_readfirstlane(
      (int)((blockIdx.x * blockDim.x + threadIdx.x) >> 6));
  const int nw = (int)((gridDim.x * blockDim.x) >> 6);
  if (gw >= PAIRS) return;

  IdxS iCur, iNext;
  load_idx(inds + (size_t)gw * KNB, iCur);
  for (int p = gw; p < PAIRS; p += nw) {
    const int pn = (p + nw < PAIRS) ? (p + nw) : gw;
    load_idx(inds + (size_t)pn * KNB, iNext);
    const int b = (p >= M_) ? 1 : 0;
    StageF S = {};
    load_stage_f(feat + (size_t)b * N_ * CIN, wnet + (size_t)p * 256,
                 addf + (size_t)p * 48, iCur, lane, S);
    const int cc = lane & 15, g = lane >> 4;
    const int soff = cc * 16 + g * 4;
    float* op = out + (size_t)p * COUT;
    const short8 a = pack_bf8(S.wf);
    #pragma unroll
    for (int t = 0; t < 4; ++t) {
      const short8 bb = pack_bf8(S.bg[t]);
      f32x4 acc = {0.f, 0.f, 0.f, 0.f};
      acc = __builtin_amdgcn_mfma_f32_16x16x32_bf16(a, bb, acc, 0, 0, 0);
      __builtin_nontemporal_store(acc, reinterpret_cast<f32x4*>(op + soff + t * 256));
    }
    {
      const short8 bb = pack_bf8(S.ad);
      f32x4 acc = {0.f, 0.f, 0.f, 0.f};
      acc = __builtin_amdgcn_mfma_f32_16x16x32_bf16(a, bb, acc, 0, 0, 0);
      if (cc < 3)
        __builtin_nontemporal_store(acc, reinterpret_cast<f32x4*>(op + soff + 1024));
    }
    #pragma unroll
    for (int j = 0; j < 16; ++j) iCur.v[j] = iNext.v[j];
  }
}

extern "C" void kernel_launch(void* const* d_in, const int* in_sizes, int n_in,
                              void* d_out, int out_size, void* d_ws, size_t ws_size,
                              hipStream_t stream) {
  const float* feat = (const float*)d_in[0];
  const int*   inds = (const int*)d_in[1];
  const float* wnet = (const float*)d_in[2];
  const float* addf = (const float*)d_in[3];
  float* outp = (float*)d_out;

  const size_t TBL_BYTES = (size_t)FELEMS * sizeof(unsigned short);  // 12.8 MB

  dim3 grid(1024), block(256);   // exactly 4 blocks/CU resident; ~24 iters/wave
  if (ws_size >= TBL_BYTES) {
    unsigned short* tbl = (unsigned short*)d_ws;
    hipLaunchKernelGGL(cvt_feat_bf16, dim3(2048), dim3(256), 0, stream, feat, tbl);
    hipLaunchKernelGGL(pconv12, grid, block, 0, stream, tbl, inds, wnet, addf, outp);
  } else {
    hipLaunchKernelGGL(pconv12_f32, grid, block, 0, stream,
                       feat, inds, wnet, addf, outp);
  }
}